// Round 17
// baseline (288.092 us; speedup 1.0000x reference)
//
#include <hip/hip_runtime.h>
#include <hip/hip_bf16.h>
#include <cstdint>

#define DD 8192
#define NROW 200
#define MT 13          // 13 M-tiles of 16 rows = 208
#define MPAD 208
#define KPV 256        // padded K for the PV GEMM
#define EPSV 1e-5f
#define BK 64
#define MT7 7
#define ABUF_BYTES (MPAD * BK * 2)   // 26624 bytes per LDS x-buffer

using short8 = __attribute__((ext_vector_type(8))) short;
using f32x4  = __attribute__((ext_vector_type(4))) float;

__device__ __forceinline__ ushort f2bf(float f) {
    union { float f; unsigned u; } c; c.f = f;
    unsigned u = c.u;
    return (ushort)((u + 0x7FFFu + ((u >> 16) & 1u)) >> 16);  // RNE
}

__device__ __forceinline__ short8 pack8(float4 a, float4 b) {
    short8 o;
    o[0]=f2bf(a.x); o[1]=f2bf(a.y); o[2]=f2bf(a.z); o[3]=f2bf(a.w);
    o[4]=f2bf(b.x); o[5]=f2bf(b.y); o[6]=f2bf(b.z); o[7]=f2bf(b.w);
    return o;
}

// fast pack via v_cvt_pk_bf16_f32 (RNE, same semantics as f2bf)
__device__ __forceinline__ short8 pack8f(f32x4 a, f32x4 b) {
    short8 o;
    union { __hip_bfloat162 h; unsigned u; } q;
    q.h = __float22bfloat162_rn(float2{a[0], a[1]}); o[0]=(short)(q.u & 0xffff); o[1]=(short)(q.u >> 16);
    q.h = __float22bfloat162_rn(float2{a[2], a[3]}); o[2]=(short)(q.u & 0xffff); o[3]=(short)(q.u >> 16);
    q.h = __float22bfloat162_rn(float2{b[0], b[1]}); o[4]=(short)(q.u & 0xffff); o[5]=(short)(q.u >> 16);
    q.h = __float22bfloat162_rn(float2{b[2], b[3]}); o[6]=(short)(q.u & 0xffff); o[7]=(short)(q.u >> 16);
    return o;
}

// ---------------- kernel 1: x (f32 [200][8192]) -> xb (bf16 [208][8192], pad rows 0)
__global__ void cvt_x(const float* __restrict__ x, ushort* __restrict__ xb) {
    int i = (blockIdx.x * 256 + threadIdx.x) * 8;
    int row = i >> 13;
    int col = i & (DD - 1);
    short8 o;
    if (row < NROW) {
        const float4* p = reinterpret_cast<const float4*>(x + (size_t)row * DD + col);
        float4 a = p[0], b = p[1];
        o = pack8(a, b);
    } else {
        for (int j = 0; j < 8; ++j) o[j] = 0;
    }
    *reinterpret_cast<short8*>(xb + i) = o;
}

#define GL(dst, ptr, OFF) \
    asm volatile("global_load_dwordx4 %0, %1, off offset:" #OFF \
                 : "=&v"(dst) : "v"(ptr) : "memory")
#define WAITV(N) asm volatile("s_waitcnt vmcnt(" #N ")" ::: "memory")
#define SB __builtin_amdgcn_sched_barrier(0)
#define RAWBAR asm volatile("s_barrier" ::: "memory")

// ---------------- kernel 2: fused QKV GEMM — R14 structure, 12 WAVES per block.
// grid 256 (1 block/CU), block 768 (12 waves): wave = (mat = w>>2, colgroup = (w>>1)&1,
// M-half = w&1). Each wave: 16 cols x 7 M-tiles (half h: tiles h*6..h*6+6; tile 6
// computed by both halves, stored by half0 only) x full K.
// x k-slice [208][64] bf16 double-buffered via gl_lds, staged by waves 0-5 with
// R14's exact sets (5/5/4/4/4/4, WAITV 9/8); waves 6-11 stage nothing (WAITV 4).
// W via inline-asm GL reg-dbuf (per-wave; duplicate cols dedup in L1/L2).
// 12 waves/CU = 3/SIMD. No partials. Full drain before epilogue.
__global__ __launch_bounds__(768) void qkv_w12(
    const ushort* __restrict__ xb,
    const float* __restrict__ Wq, const float* __restrict__ Wk, const float* __restrict__ Wv,
    const float* __restrict__ bq, const float* __restrict__ bk, const float* __restrict__ bv,
    ushort* __restrict__ qb, ushort* __restrict__ kb, ushort* __restrict__ vt)
{
    __shared__ char L[2 * ABUF_BYTES];   // 53,248 B -> 1 block/CU

    const int cb   = blockIdx.x;        // col-block (32 cols, shared by 3 mats)
    const int t    = threadIdx.x;
    const int lane = t & 63;
    const int wave = t >> 6;            // 0..11
    const int mat  = wave >> 2;         // 0..2
    const int cg   = (wave >> 1) & 1;   // colgroup
    const int mh   = wave & 1;          // M-half: tiles mh*6 .. mh*6+6
    const int c    = lane & 15;
    const int kgrp = lane >> 4;
    const int ncol = cb * 32 + cg * 16 + c;

    const float* W    = (mat == 0) ? Wq : (mat == 1 ? Wk : Wv);
    const float* bias = (mat == 0) ? bq : (mat == 1 ? bk : bv);
    const float* wq   = W + (size_t)ncol * DD + kgrp * 8;

    // x staging (R14-exact): per gl_lds, 64 lanes x 16B = 8 rows x 128B linear;
    // swizzled global source so content at (row, slot16B) holds k-slot = slot ^ (row&7).
    const ushort* sbase = xb + (size_t)(lane >> 3) * DD
                             + (size_t)(((lane & 7) ^ ((lane >> 3) & 7)) * 8);
    // 26 groups of 8 rows; staging waves 0-5: groups {w, w+6, w+12, w+18, w+24} < 26
    // -> 5/5/4/4/4/4. Waves 6-11: none.

    // ds_read a-frag (tile tt, chunk j): row = tt*16+c, slot = (j*4+kgrp) ^ (c&7)
    const int b0off = c * 128 + ((kgrp ^ (c & 7)) * 16);
    const int b1off = b0off ^ 64;

    f32x4 acc[MT7];
    #pragma unroll
    for (int m = 0; m < MT7; ++m)
        for (int r = 0; r < 4; ++r) acc[m][r] = 0.f;

    f32x4 uA0, uA1, uA2, uA3, uB0, uB1, uB2, uB3;

#define STAGE(B, KK) { if (wave < 6) { _Pragma("unroll") for (int j = 0; j < 5; ++j) { \
        int g = wave + 6 * j; \
        if (g < 26) { \
            __builtin_amdgcn_global_load_lds( \
                (const __attribute__((address_space(1))) void*)(sbase + (KK) + (size_t)g * 8 * DD), \
                (__attribute__((address_space(3))) void*)(L + (B) + g * 1024), \
                16, 0, 0); } } } }

#define COMPUTE(RB, bb0, bb1) { _Pragma("unroll") for (int m = 0; m < MT7; ++m) { \
        int tt = mh * 6 + m; \
        short8 a0 = *reinterpret_cast<const short8*>(L + (RB) + tt * 2048 + b0off); \
        acc[m] = __builtin_amdgcn_mfma_f32_16x16x32_bf16(a0, bb0, acc[m], 0, 0, 0); \
        short8 a1 = *reinterpret_cast<const short8*>(L + (RB) + tt * 2048 + b1off); \
        acc[m] = __builtin_amdgcn_mfma_f32_16x16x32_bf16(a1, bb1, acc[m], 0, 0, 0); } }

// phase: stage(t+1) -> other buf; WAITV retires {stage(t), W(t)}; pack W(t);
// issue W(t+2) into freed regs; barrier; MFMA from buf(t); barrier.
#define PHASE(RB, UC) { \
        STAGE((RB) ^ ABUF_BYTES, kn); \
        kn = (kn + BK) & (DD - 1); \
        if (wave >= 6)     { WAITV(4); } \
        else if (wave < 2) { WAITV(9); } \
        else               { WAITV(8); } \
        SB; \
        short8 bb0 = pack8f(UC##0, UC##1); \
        short8 bb1 = pack8f(UC##2, UC##3); \
        GL(UC##0, wq + k2, 0); \
        GL(UC##1, wq + k2, 16); \
        GL(UC##2, wq + k2, 128); \
        GL(UC##3, wq + k2, 144); \
        k2 = (k2 + BK) & (DD - 1); \
        RAWBAR; \
        COMPUTE(RB, bb0, bb1); \
        asm volatile("s_waitcnt lgkmcnt(0)" ::: "memory"); \
        RAWBAR; }

    // ---------------- prologue: stage(0) -> buf0; W(0) -> uA; W(1) -> uB
    int kn = BK;     // next stage k
    int k2 = 2 * BK; // next W k
    STAGE(0, 0);
    GL(uA0, wq, 0);  GL(uA1, wq, 16);  GL(uA2, wq, 128);  GL(uA3, wq, 144);
    GL(uB0, wq + BK, 0); GL(uB1, wq + BK, 16); GL(uB2, wq + BK, 128); GL(uB3, wq + BK, 144);
    // queue: [stage0:sw, W0:4, W1:4]  (sw = 5/4 for waves 0-5, 0 for waves 6-11)

    #pragma unroll 1
    for (int it = 0; it < DD / (2 * BK); ++it) {
        PHASE(0, uA);            // even: read buf0, consume W(even)
        PHASE(ABUF_BYTES, uB);   // odd:  read buf1, consume W(odd)
    }
#undef PHASE
#undef COMPUTE
#undef STAGE

    // drain all outstanding (dead prefetches) before epilogue stores
    asm volatile("s_waitcnt vmcnt(0) lgkmcnt(0)" ::: "memory");
    RAWBAR;

    // ---------------- epilogue: direct stores. half0 stores tiles 0-6, half1 tiles 7-12
    // (local m -> global tile mh*6 + m; half1 skips m=0, its duplicate of tile 6).
    const float bv0 = bias[ncol];
    if (mat < 2) {
        ushort* outb = (mat == 0) ? qb : kb;
        #pragma unroll
        for (int m = 0; m < MT7; ++m) {
            if (m >= mh) {
                #pragma unroll
                for (int r = 0; r < 4; ++r) {
                    int row = (mh * 6 + m) * 16 + kgrp * 4 + r;   // C/D: col=lane&15, row=(lane>>4)*4+r
                    outb[(size_t)row * DD + ncol] = f2bf(acc[m][r] + bv0);
                }
            }
        }
    } else {
        // write V directly transposed: vt[n][k] = v[k][n], bf16
        #pragma unroll
        for (int m = 0; m < MT7; ++m) {
            if (m >= mh) {
                #pragma unroll
                for (int r = 0; r < 4; ++r) {
                    int row = (mh * 6 + m) * 16 + kgrp * 4 + r;
                    vt[(size_t)ncol * KPV + row] = f2bf(acc[m][r] + bv0);
                }
            }
        }
    }
}

// ---------------- kernel 4: s = q @ k^T  (f32 [208][208]); grid (13,13), 4-wave K-split
__global__ __launch_bounds__(256) void sgemm(const ushort* __restrict__ qb, const ushort* __restrict__ kb,
                                             float* __restrict__ sbuf) {
    const int bm = blockIdx.y, bn = blockIdx.x;
    const int lane  = threadIdx.x & 63;
    const int wave  = threadIdx.x >> 6;
    const int col16 = lane & 15, kgrp = lane >> 4;
    const ushort* ap = qb + (size_t)(bm * 16 + col16) * DD + kgrp * 8;
    const ushort* bp = kb + (size_t)(bn * 16 + col16) * DD + kgrp * 8;
    f32x4 acc;
    for (int r = 0; r < 4; ++r) acc[r] = 0.f;
    const int kend = (wave + 1) * 2048;
    for (int k0 = wave * 2048; k0 < kend; k0 += 32) {
        short8 a = *reinterpret_cast<const short8*>(ap + k0);
        short8 b = *reinterpret_cast<const short8*>(bp + k0);
        acc = __builtin_amdgcn_mfma_f32_16x16x32_bf16(a, b, acc, 0, 0, 0);
    }
    __shared__ f32x4 red[4][64];
    red[wave][lane] = acc;
    __syncthreads();
    if (wave == 0) {
        f32x4 s = red[0][lane];
        for (int j = 1; j < 4; ++j) { f32x4 o = red[j][lane]; for (int r = 0; r < 4; ++r) s[r] += o[r]; }
        for (int r = 0; r < 4; ++r)
            sbuf[(size_t)(bm * 16 + kgrp * 4 + r) * MPAD + bn * 16 + col16] = s[r];
    }
}

// ---------------- kernel 5: per-row mean/var(ddof=1) -> sin -> softmax -> P bf16 [208][256] (pads 0)
__global__ __launch_bounds__(256) void rownorm(const float* __restrict__ sbuf, ushort* __restrict__ pb) {
    const int row = blockIdx.x;
    const int t = threadIdx.x;
    if (row >= NROW) { pb[(size_t)row * KPV + t] = 0; return; }
    __shared__ float part[4];
    const int lane = t & 63, wave = t >> 6;
    float x = (t < NROW) ? sbuf[(size_t)row * MPAD + t] : 0.f;

    float s = x;
    for (int m = 32; m; m >>= 1) s += __shfl_xor(s, m, 64);
    if (lane == 0) part[wave] = s;
    __syncthreads();
    float mean = (part[0] + part[1] + part[2] + part[3]) * (1.f / 200.f);

    float d = (t < NROW) ? (x - mean) : 0.f;
    float s2 = d * d;
    for (int m = 32; m; m >>= 1) s2 += __shfl_xor(s2, m, 64);
    __syncthreads();
    if (lane == 0) part[wave] = s2;
    __syncthreads();
    float var = (part[0] + part[1] + part[2] + part[3]) * (1.f / 199.f);

    float inv = 1.f / sqrtf(var + EPSV);
    float y = sinf(d * inv);
    const float inv_cc = 1.f / 90.50966799187809f;   // 1/sqrt(8192)
    float e = (t < NROW) ? expf(y * inv_cc) : 0.f;

    float se = e;
    for (int m = 32; m; m >>= 1) se += __shfl_xor(se, m, 64);
    __syncthreads();
    if (lane == 0) part[wave] = se;
    __syncthreads();
    float tot = part[0] + part[1] + part[2] + part[3];
    pb[(size_t)row * KPV + t] = (t < NROW) ? f2bf(e / tot) : (ushort)0;
}

// ---------------- kernel 6: out = P @ V  via out[m][n] = sum_k P[m][k] * vt[n][k]
__global__ __launch_bounds__(256) void pv_gemm(const ushort* __restrict__ pb, const ushort* __restrict__ vt,
                                               float* __restrict__ out) {
    const int lane  = threadIdx.x & 63;
    const int wave  = threadIdx.x >> 6;
    const int col16 = lane & 15, kgrp = lane >> 4;
    const int ncol  = blockIdx.x * 64 + wave * 16 + col16;
    const ushort* ap = pb + (size_t)col16 * KPV + kgrp * 8;
    const ushort* bp = vt + (size_t)ncol  * KPV + kgrp * 8;
    f32x4 acc[MT];
    for (int m = 0; m < MT; ++m)
        for (int r = 0; r < 4; ++r) acc[m][r] = 0.f;
    for (int k0 = 0; k0 < KPV; k0 += 32) {
        short8 b = *reinterpret_cast<const short8*>(bp + k0);
        #pragma unroll
        for (int m = 0; m < MT; ++m) {
            short8 a = *reinterpret_cast<const short8*>(ap + (size_t)m * 16 * KPV + k0);
            acc[m] = __builtin_amdgcn_mfma_f32_16x16x32_bf16(a, b, acc[m], 0, 0, 0);
        }
    }
    for (int m = 0; m < MT; ++m)
        for (int r = 0; r < 4; ++r) {
            int row = m * 16 + kgrp * 4 + r;
            if (row < NROW) out[(size_t)row * DD + ncol] = acc[m][r];
        }
}

extern "C" void kernel_launch(void* const* d_in, const int* in_sizes, int n_in,
                              void* d_out, int out_size, void* d_ws, size_t ws_size,
                              hipStream_t stream) {
    const float* x  = (const float*)d_in[0];
    const float* Wq = (const float*)d_in[1];
    const float* bq = (const float*)d_in[2];
    const float* Wk = (const float*)d_in[3];
    const float* bk = (const float*)d_in[4];
    const float* Wv = (const float*)d_in[5];
    const float* bv = (const float*)d_in[6];
    float* out = (float*)d_out;

    char* ws = (char*)d_ws;
    ushort* xb   = (ushort*)(ws);                       // 208*8192*2 = 3,407,872
    ushort* qb   = (ushort*)(ws + 3407872);             // 3,407,872
    ushort* kb   = (ushort*)(ws + 6815744);             // 3,407,872
    ushort* vt   = (ushort*)(ws + 10223616);            // 8192*256*2 = 4,194,304
    float*  sbuf = (float*)(ws + 14417920);             // 208*208*4 = 173,056
    ushort* pb   = (ushort*)(ws + 14590976);            // 208*256*2 = 106,496
    // total 14,697,472 bytes

    cvt_x<<<832, 256, 0, stream>>>(x, xb);
    qkv_w12<<<256, 768, 0, stream>>>(xb, Wq, Wk, Wv, bq, bk, bv, qb, kb, vt);
    sgemm<<<dim3(13, 13), 256, 0, stream>>>(qb, kb, sbuf);
    rownorm<<<208, 256, 0, stream>>>(sbuf, pb);
    pv_gemm<<<128, 256, 0, stream>>>(pb, vt, out);
}

// Round 18
// 251.469 us; speedup vs baseline: 1.1456x; 1.1456x over previous
//
#include <hip/hip_runtime.h>
#include <hip/hip_bf16.h>
#include <cstdint>

#define DD 8192
#define NROW 200
#define MT 13          // 13 M-tiles of 16 rows = 208
#define MPAD 208
#define KPV 256        // padded K for the PV GEMM
#define EPSV 1e-5f
#define BK 128
#define ABUF_BYTES (MPAD * BK * 2)   // 53248 bytes per LDS x-buffer

using short8 = __attribute__((ext_vector_type(8))) short;
using f32x4  = __attribute__((ext_vector_type(4))) float;

__device__ __forceinline__ ushort f2bf(float f) {
    union { float f; unsigned u; } c; c.f = f;
    unsigned u = c.u;
    return (ushort)((u + 0x7FFFu + ((u >> 16) & 1u)) >> 16);  // RNE
}

__device__ __forceinline__ short8 pack8(float4 a, float4 b) {
    short8 o;
    o[0]=f2bf(a.x); o[1]=f2bf(a.y); o[2]=f2bf(a.z); o[3]=f2bf(a.w);
    o[4]=f2bf(b.x); o[5]=f2bf(b.y); o[6]=f2bf(b.z); o[7]=f2bf(b.w);
    return o;
}

// fast pack via v_cvt_pk_bf16_f32 (RNE, same semantics as f2bf)
__device__ __forceinline__ short8 pack8f(f32x4 a, f32x4 b) {
    short8 o;
    union { __hip_bfloat162 h; unsigned u; } q;
    q.h = __float22bfloat162_rn(float2{a[0], a[1]}); o[0]=(short)(q.u & 0xffff); o[1]=(short)(q.u >> 16);
    q.h = __float22bfloat162_rn(float2{a[2], a[3]}); o[2]=(short)(q.u & 0xffff); o[3]=(short)(q.u >> 16);
    q.h = __float22bfloat162_rn(float2{b[0], b[1]}); o[4]=(short)(q.u & 0xffff); o[5]=(short)(q.u >> 16);
    q.h = __float22bfloat162_rn(float2{b[2], b[3]}); o[6]=(short)(q.u & 0xffff); o[7]=(short)(q.u >> 16);
    return o;
}

// ---------------- kernel 1: x (f32 [200][8192]) -> xb (bf16 [208][8192], pad rows 0)
__global__ void cvt_x(const float* __restrict__ x, ushort* __restrict__ xb) {
    int i = (blockIdx.x * 256 + threadIdx.x) * 8;
    int row = i >> 13;
    int col = i & (DD - 1);
    short8 o;
    if (row < NROW) {
        const float4* p = reinterpret_cast<const float4*>(x + (size_t)row * DD + col);
        float4 a = p[0], b = p[1];
        o = pack8(a, b);
    } else {
        for (int j = 0; j < 8; ++j) o[j] = 0;
    }
    *reinterpret_cast<short8*>(xb + i) = o;
}

#define GL(dst, ptr, OFF) \
    asm volatile("global_load_dwordx4 %0, %1, off offset:" #OFF \
                 : "=&v"(dst) : "v"(ptr) : "memory")
#define WAITV(N) asm volatile("s_waitcnt vmcnt(" #N ")" ::: "memory")
#define SB __builtin_amdgcn_sched_barrier(0)
#define RAWBAR asm volatile("s_barrier" ::: "memory")

// ---------------- kernel 2: fused QKV GEMM — R14 structure with BK=128 (64 phases).
// grid 256 (1 block/CU), block 384 (6 waves): wave = (mat = w>>1, colgroup = w&1).
// Each wave: 16 cols x 13 M-tiles x full K. x k-slice [208][128] bf16 double-buffered
// via gl_lds (swizzled source; groups of 4 rows x 256B; wave-parity term in swizzle),
// staged 9/9/9/9/8/8 across waves 0-5 (WAITV 17/16 keeps W(t+1):8 + stage(t+1):sw);
// W via inline-asm GL reg-dbuf (8 dwordx4/phase), 2 phases ahead. 2 raw barriers/phase,
// half as many phases as R14. 1 block/CU, 6 waves/CU. No partials.
__global__ __launch_bounds__(384) void qkv_b128(
    const ushort* __restrict__ xb,
    const float* __restrict__ Wq, const float* __restrict__ Wk, const float* __restrict__ Wv,
    const float* __restrict__ bq, const float* __restrict__ bk, const float* __restrict__ bv,
    ushort* __restrict__ qb, ushort* __restrict__ kb, ushort* __restrict__ vt)
{
    __shared__ char L[2 * ABUF_BYTES];   // 106,496 B -> 1 block/CU

    const int cb   = blockIdx.x;        // col-block (32 cols, shared by 3 mats)
    const int t    = threadIdx.x;
    const int lane = t & 63;
    const int wave = t >> 6;            // 0..5
    const int mat  = wave >> 1;         // 0..2
    const int cg   = wave & 1;          // colgroup
    const int c    = lane & 15;
    const int kgrp = lane >> 4;
    const int ncol = cb * 32 + cg * 16 + c;

    const float* W    = (mat == 0) ? Wq : (mat == 1 ? Wk : Wv);
    const float* bias = (mat == 0) ? bq : (mat == 1 ? bk : bv);
    const float* wq   = W + (size_t)ncol * DD + kgrp * 8;

    // x staging: per gl_lds, 64 lanes x 16B = 4 rows x 256B linear.
    // Content at (row, slot16B of 16) must hold k-slot = slot ^ (row&7).
    // lane l: local row = l>>4 (0..3), slot = l&15. Global row = 4g + (l>>4);
    // row&7 = 4*(g&1) + (l>>4), and g = wave + 6j -> g&1 = wave&1 (constant).
    const ushort* sbase = xb + (size_t)(lane >> 4) * DD
                             + (size_t)(((lane & 15) ^ ((wave & 1) * 4 + (lane >> 4))) * 8);
    // 52 groups of 4 rows; wave w stages groups {w+6j, j=0..8} < 52 -> 9/9/9/9/8/8.

    // ds_read a-frag (tile m, chunk j=0..3): row = m*16+c,
    // phys slot = (j*4+kgrp) ^ (c&7) -> byte = b0off ^ (64*j)
    const int b0off = c * 256 + ((kgrp ^ (c & 7)) * 16);

    f32x4 acc[MT];
    #pragma unroll
    for (int m = 0; m < MT; ++m)
        for (int r = 0; r < 4; ++r) acc[m][r] = 0.f;

    f32x4 uA0, uA1, uA2, uA3, uA4, uA5, uA6, uA7;
    f32x4 uB0, uB1, uB2, uB3, uB4, uB5, uB6, uB7;

#define STAGE(B, KK) { _Pragma("unroll") for (int j = 0; j < 9; ++j) { \
        int g = wave + 6 * j; \
        if (g < 52) { \
            __builtin_amdgcn_global_load_lds( \
                (const __attribute__((address_space(1))) void*)(sbase + (KK) + (size_t)g * 4 * DD), \
                (__attribute__((address_space(3))) void*)(L + (B) + g * 1024), \
                16, 0, 0); } } }

#define COMPUTE(RB, bb0, bb1, bb2, bb3) { _Pragma("unroll") for (int m = 0; m < MT; ++m) { \
        short8 a0 = *reinterpret_cast<const short8*>(L + (RB) + m * 4096 + b0off); \
        acc[m] = __builtin_amdgcn_mfma_f32_16x16x32_bf16(a0, bb0, acc[m], 0, 0, 0); \
        short8 a1 = *reinterpret_cast<const short8*>(L + (RB) + m * 4096 + (b0off ^ 64)); \
        acc[m] = __builtin_amdgcn_mfma_f32_16x16x32_bf16(a1, bb1, acc[m], 0, 0, 0); \
        short8 a2 = *reinterpret_cast<const short8*>(L + (RB) + m * 4096 + (b0off ^ 128)); \
        acc[m] = __builtin_amdgcn_mfma_f32_16x16x32_bf16(a2, bb2, acc[m], 0, 0, 0); \
        short8 a3 = *reinterpret_cast<const short8*>(L + (RB) + m * 4096 + (b0off ^ 192)); \
        acc[m] = __builtin_amdgcn_mfma_f32_16x16x32_bf16(a3, bb3, acc[m], 0, 0, 0); } }

// phase: stage(t+1) -> other buf; WAITV retires {stage(t), W(t)}; pack W(t) (4 pairs);
// issue W(t+2) into freed regs; barrier; MFMA from buf(t); barrier.
#define PHASE(RB, UC) { \
        STAGE((RB) ^ ABUF_BYTES, kn); \
        kn = (kn + BK) & (DD - 1); \
        if (wave < 4) { WAITV(17); } else { WAITV(16); } \
        SB; \
        short8 bb0 = pack8f(UC##0, UC##1); \
        short8 bb1 = pack8f(UC##2, UC##3); \
        short8 bb2 = pack8f(UC##4, UC##5); \
        short8 bb3 = pack8f(UC##6, UC##7); \
        GL(UC##0, wq + k2, 0); \
        GL(UC##1, wq + k2, 16); \
        GL(UC##2, wq + k2, 128); \
        GL(UC##3, wq + k2, 144); \
        GL(UC##4, wq + k2, 256); \
        GL(UC##5, wq + k2, 272); \
        GL(UC##6, wq + k2, 384); \
        GL(UC##7, wq + k2, 400); \
        k2 = (k2 + BK) & (DD - 1); \
        RAWBAR; \
        COMPUTE(RB, bb0, bb1, bb2, bb3); \
        asm volatile("s_waitcnt lgkmcnt(0)" ::: "memory"); \
        RAWBAR; }

    // ---------------- prologue: stage(0) -> buf0; W(0) -> uA; W(1) -> uB
    int kn = BK;     // next stage k (elements)
    int k2 = 2 * BK; // next W k (floats)
    STAGE(0, 0);
    GL(uA0, wq, 0);   GL(uA1, wq, 16);  GL(uA2, wq, 128); GL(uA3, wq, 144);
    GL(uA4, wq, 256); GL(uA5, wq, 272); GL(uA6, wq, 384); GL(uA7, wq, 400);
    GL(uB0, wq + BK, 0);   GL(uB1, wq + BK, 16);  GL(uB2, wq + BK, 128); GL(uB3, wq + BK, 144);
    GL(uB4, wq + BK, 256); GL(uB5, wq + BK, 272); GL(uB6, wq + BK, 384); GL(uB7, wq + BK, 400);
    // queue: [stage0:sw, W0:8, W1:8]

    #pragma unroll 1
    for (int it = 0; it < DD / (2 * BK); ++it) {
        PHASE(0, uA);            // even: read buf0, consume W(even)
        PHASE(ABUF_BYTES, uB);   // odd:  read buf1, consume W(odd)
    }
#undef PHASE
#undef COMPUTE
#undef STAGE

    // drain all outstanding (dead prefetches) before epilogue stores
    asm volatile("s_waitcnt vmcnt(0) lgkmcnt(0)" ::: "memory");
    RAWBAR;

    // ---------------- epilogue: direct stores (no partials)
    const float bv0 = bias[ncol];
    if (mat < 2) {
        ushort* outb = (mat == 0) ? qb : kb;
        #pragma unroll
        for (int m = 0; m < MT; ++m)
            for (int r = 0; r < 4; ++r) {
                int row = m * 16 + kgrp * 4 + r;   // C/D: col=lane&15, row=(lane>>4)*4+r
                outb[(size_t)row * DD + ncol] = f2bf(acc[m][r] + bv0);
            }
    } else {
        // write V directly transposed: vt[n][k] = v[k][n], bf16
        #pragma unroll
        for (int m = 0; m < MT; ++m)
            for (int r = 0; r < 4; ++r) {
                int row = m * 16 + kgrp * 4 + r;
                vt[(size_t)ncol * KPV + row] = f2bf(acc[m][r] + bv0);
            }
    }
}

// ---------------- kernel 4: s = q @ k^T  (f32 [208][208]); grid (13,13), 4-wave K-split
__global__ __launch_bounds__(256) void sgemm(const ushort* __restrict__ qb, const ushort* __restrict__ kb,
                                             float* __restrict__ sbuf) {
    const int bm = blockIdx.y, bn = blockIdx.x;
    const int lane  = threadIdx.x & 63;
    const int wave  = threadIdx.x >> 6;
    const int col16 = lane & 15, kgrp = lane >> 4;
    const ushort* ap = qb + (size_t)(bm * 16 + col16) * DD + kgrp * 8;
    const ushort* bp = kb + (size_t)(bn * 16 + col16) * DD + kgrp * 8;
    f32x4 acc;
    for (int r = 0; r < 4; ++r) acc[r] = 0.f;
    const int kend = (wave + 1) * 2048;
    for (int k0 = wave * 2048; k0 < kend; k0 += 32) {
        short8 a = *reinterpret_cast<const short8*>(ap + k0);
        short8 b = *reinterpret_cast<const short8*>(bp + k0);
        acc = __builtin_amdgcn_mfma_f32_16x16x32_bf16(a, b, acc, 0, 0, 0);
    }
    __shared__ f32x4 red[4][64];
    red[wave][lane] = acc;
    __syncthreads();
    if (wave == 0) {
        f32x4 s = red[0][lane];
        for (int j = 1; j < 4; ++j) { f32x4 o = red[j][lane]; for (int r = 0; r < 4; ++r) s[r] += o[r]; }
        for (int r = 0; r < 4; ++r)
            sbuf[(size_t)(bm * 16 + kgrp * 4 + r) * MPAD + bn * 16 + col16] = s[r];
    }
}

// ---------------- kernel 5: per-row mean/var(ddof=1) -> sin -> softmax -> P bf16 [208][256] (pads 0)
__global__ __launch_bounds__(256) void rownorm(const float* __restrict__ sbuf, ushort* __restrict__ pb) {
    const int row = blockIdx.x;
    const int t = threadIdx.x;
    if (row >= NROW) { pb[(size_t)row * KPV + t] = 0; return; }
    __shared__ float part[4];
    const int lane = t & 63, wave = t >> 6;
    float x = (t < NROW) ? sbuf[(size_t)row * MPAD + t] : 0.f;

    float s = x;
    for (int m = 32; m; m >>= 1) s += __shfl_xor(s, m, 64);
    if (lane == 0) part[wave] = s;
    __syncthreads();
    float mean = (part[0] + part[1] + part[2] + part[3]) * (1.f / 200.f);

    float d = (t < NROW) ? (x - mean) : 0.f;
    float s2 = d * d;
    for (int m = 32; m; m >>= 1) s2 += __shfl_xor(s2, m, 64);
    __syncthreads();
    if (lane == 0) part[wave] = s2;
    __syncthreads();
    float var = (part[0] + part[1] + part[2] + part[3]) * (1.f / 199.f);

    float inv = 1.f / sqrtf(var + EPSV);
    float y = sinf(d * inv);
    const float inv_cc = 1.f / 90.50966799187809f;   // 1/sqrt(8192)
    float e = (t < NROW) ? expf(y * inv_cc) : 0.f;

    float se = e;
    for (int m = 32; m; m >>= 1) se += __shfl_xor(se, m, 64);
    __syncthreads();
    if (lane == 0) part[wave] = se;
    __syncthreads();
    float tot = part[0] + part[1] + part[2] + part[3];
    pb[(size_t)row * KPV + t] = (t < NROW) ? f2bf(e / tot) : (ushort)0;
}

// ---------------- kernel 6: out = P @ V  via out[m][n] = sum_k P[m][k] * vt[n][k]
__global__ __launch_bounds__(256) void pv_gemm(const ushort* __restrict__ pb, const ushort* __restrict__ vt,
                                               float* __restrict__ out) {
    const int lane  = threadIdx.x & 63;
    const int wave  = threadIdx.x >> 6;
    const int col16 = lane & 15, kgrp = lane >> 4;
    const int ncol  = blockIdx.x * 64 + wave * 16 + col16;
    const ushort* ap = pb + (size_t)col16 * KPV + kgrp * 8;
    const ushort* bp = vt + (size_t)ncol  * KPV + kgrp * 8;
    f32x4 acc[MT];
    for (int m = 0; m < MT; ++m)
        for (int r = 0; r < 4; ++r) acc[m][r] = 0.f;
    for (int k0 = 0; k0 < KPV; k0 += 32) {
        short8 b = *reinterpret_cast<const short8*>(bp + k0);
        #pragma unroll
        for (int m = 0; m < MT; ++m) {
            short8 a = *reinterpret_cast<const short8*>(ap + (size_t)m * 16 * KPV + k0);
            acc[m] = __builtin_amdgcn_mfma_f32_16x16x32_bf16(a, b, acc[m], 0, 0, 0);
        }
    }
    for (int m = 0; m < MT; ++m)
        for (int r = 0; r < 4; ++r) {
            int row = m * 16 + kgrp * 4 + r;
            if (row < NROW) out[(size_t)row * DD + ncol] = acc[m][r];
        }
}

extern "C" void kernel_launch(void* const* d_in, const int* in_sizes, int n_in,
                              void* d_out, int out_size, void* d_ws, size_t ws_size,
                              hipStream_t stream) {
    const float* x  = (const float*)d_in[0];
    const float* Wq = (const float*)d_in[1];
    const float* bq = (const float*)d_in[2];
    const float* Wk = (const float*)d_in[3];
    const float* bk = (const float*)d_in[4];
    const float* Wv = (const float*)d_in[5];
    const float* bv = (const float*)d_in[6];
    float* out = (float*)d_out;

    char* ws = (char*)d_ws;
    ushort* xb   = (ushort*)(ws);                       // 208*8192*2 = 3,407,872
    ushort* qb   = (ushort*)(ws + 3407872);             // 3,407,872
    ushort* kb   = (ushort*)(ws + 6815744);             // 3,407,872
    ushort* vt   = (ushort*)(ws + 10223616);            // 8192*256*2 = 4,194,304
    float*  sbuf = (float*)(ws + 14417920);             // 208*208*4 = 173,056
    ushort* pb   = (ushort*)(ws + 14590976);            // 208*256*2 = 106,496
    // total 14,697,472 bytes

    cvt_x<<<832, 256, 0, stream>>>(x, xb);
    qkv_b128<<<256, 384, 0, stream>>>(xb, Wq, Wk, Wv, bq, bk, bv, qb, kb, vt);
    sgemm<<<dim3(13, 13), 256, 0, stream>>>(qb, kb, sbuf);
    rownorm<<<208, 256, 0, stream>>>(sbuf, pb);
    pv_gemm<<<128, 256, 0, stream>>>(pb, vt, out);
}